// Round 1
// baseline (11.160 us; speedup 1.0000x reference)
//
#include <hip/hip_runtime.h>

// WavetableModel: out[n] = sum_t exp(log_norm - 0.5*z^2) * table[t] / (peak + 1e-8)
//   z = (t/4095 - mu_n)/sigma,  mu_n = frac((n+1)*|f0|),  sigma = 0.01+1e-8
// Gaussian is ~41 indices wide (sigma*4095); truncate at +-256 taps (+-6.25 sigma).

#define NS   32768
#define TS   4096
#define BLK  256
#define SPB  (BLK / 4)       // 64 samples per block (4 lanes per sample)
#define NBLK (NS / SPB)      // 512 blocks
#define HALF 256             // half-window in taps
#define NCHUNK 132           // float4 chunks per sample (528 taps incl. align slop)
#define TPAD 4608            // table + zero pad for clipped top windows

__global__ __launch_bounds__(BLK) void wt_kernel(const float* __restrict__ f0p,
                                                 const float* __restrict__ table,
                                                 float* __restrict__ out)
{
    __shared__ float tab[TPAD];
    const int tid = threadIdx.x;
    {
        const float4* t4 = (const float4*)table;
        float4* s4 = (float4*)tab;
        for (int i = tid; i < TS / 4; i += BLK) s4[i] = t4[i];
        for (int i = TS / 4 + tid; i < TPAD / 4; i += BLK)
            s4[i] = make_float4(0.f, 0.f, 0.f, 0.f);
    }
    const float f0a = fabsf(f0p[0]);
    __syncthreads();

    const int g = blockIdx.x * BLK + tid;
    const int n = g >> 2;        // sample index
    const int j = g & 3;         // lane-within-sample

    const double sigma = 0.01 + 1e-8;
    const float  log_norm = 3.6862306527839187f;   // -ln(sigma) - 0.5*ln(2*pi)

    // mu exactly (double): frac((n+1)*|f0|)
    const double mu = fmod((double)(n + 1) * (double)f0a, 1.0);

    // normalizer: window value at nearest grid point
    const int tc = (int)(mu * 4095.0 + 0.5);
    const float zsf = (float)(((double)tc * (1.0 / 4095.0) - mu) / sigma);
    const float peak = __expf(fmaf(-0.5f * zsf, zsf, log_norm));
    const float denom = peak + 1e-8f;

    int t0 = tc - HALF;
    t0 = (t0 < 0) ? 0 : t0;
    t0 &= ~3;                    // float4 alignment

    const float dz = (float)(1.0 / (4095.0 * sigma));
    const float z0 = (float)(((double)t0 * (1.0 / 4095.0) - mu) / sigma);

    const float4* __restrict__ src = (const float4*)(tab + t0);
    float acc = 0.f;
    #pragma unroll 3
    for (int c = j; c < NCHUNK; c += 4) {
        const float4 v = src[c];
        const float e0 = (float)(4 * c);
        float z;
        z = fmaf(e0,        dz, z0); acc = fmaf(__expf(fmaf(-0.5f * z, z, log_norm)), v.x, acc);
        z = fmaf(e0 + 1.f,  dz, z0); acc = fmaf(__expf(fmaf(-0.5f * z, z, log_norm)), v.y, acc);
        z = fmaf(e0 + 2.f,  dz, z0); acc = fmaf(__expf(fmaf(-0.5f * z, z, log_norm)), v.z, acc);
        z = fmaf(e0 + 3.f,  dz, z0); acc = fmaf(__expf(fmaf(-0.5f * z, z, log_norm)), v.w, acc);
    }

    // reduce 4 lanes -> sample
    acc += __shfl_xor(acc, 1);
    acc += __shfl_xor(acc, 2);
    if (j == 0) out[n] = acc / denom;
}

extern "C" void kernel_launch(void* const* d_in, const int* in_sizes, int n_in,
                              void* d_out, int out_size, void* d_ws, size_t ws_size,
                              hipStream_t stream)
{
    const float* f0    = (const float*)d_in[1];   // d_in[0] = x (unused by the math)
    const float* table = (const float*)d_in[2];
    float* out = (float*)d_out;
    wt_kernel<<<dim3(NBLK), dim3(BLK), 0, stream>>>(f0, table, out);
}

// Round 2
// 10.388 us; speedup vs baseline: 1.0743x; 1.0743x over previous
//
#include <hip/hip_runtime.h>

// WavetableModel: out[n] = sum_t exp(log_norm - 0.5*z^2) * table[t] / (peak + 1e-8)
//   z = (t/4095 - mu_n)/sigma,  mu_n = frac((n+1)*|f0|),  sigma = 0.01+1e-8
// Gaussian is ~41 indices wide (sigma*4095); truncate at +-208 taps (+-5.07 sigma):
// tail mass ~6e-5 absolute vs threshold 2.05.

#define NS   32768
#define TS   4096
#define BLK  256
#define LPS  8               // lanes per sample
#define SPB  (BLK / LPS)     // 32 samples per block
#define NBLK (NS / SPB)      // 1024 blocks -> 16 waves/CU
#define HALF 208             // half-window in taps
#define NCHUNK 104           // float4 chunks per sample (416 taps)
#define TPAD 4352            // table + zero pad for clipped top windows (3884+416=4300)

__global__ __launch_bounds__(BLK) void wt_kernel(const float* __restrict__ f0p,
                                                 const float* __restrict__ table,
                                                 float* __restrict__ out)
{
    __shared__ float tab[TPAD];
    const int tid = threadIdx.x;
    {
        const float4* t4 = (const float4*)table;
        float4* s4 = (float4*)tab;
        #pragma unroll
        for (int i = tid; i < TS / 4; i += BLK) s4[i] = t4[i];
        for (int i = TS / 4 + tid; i < TPAD / 4; i += BLK)
            s4[i] = make_float4(0.f, 0.f, 0.f, 0.f);
    }
    const float f0a = fabsf(f0p[0]);
    __syncthreads();

    const int g = blockIdx.x * BLK + tid;
    const int n = g >> 3;        // sample index
    const int j = g & (LPS - 1); // lane-within-sample

    const double sigma = 0.01 + 1e-8;
    const float  log_norm = 3.6862306527839187f;   // -ln(sigma) - 0.5*ln(2*pi)

    // mu exactly (double): frac((n+1)*|f0|)
    const double mu = fmod((double)(n + 1) * (double)f0a, 1.0);

    // normalizer: window value at nearest grid point
    const int tc = (int)(mu * 4095.0 + 0.5);
    const float zsf = (float)(((double)tc * (1.0 / 4095.0) - mu) / sigma);
    const float peak = __expf(fmaf(-0.5f * zsf, zsf, log_norm));
    const float denom = peak + 1e-8f;

    int t0 = tc - HALF;
    t0 = (t0 < 0) ? 0 : t0;
    t0 &= ~3;                    // float4 alignment

    const float dz = (float)(1.0 / (4095.0 * sigma));
    const float z0 = (float)(((double)t0 * (1.0 / 4095.0) - mu) / sigma);

    const float4* __restrict__ src = (const float4*)(tab + t0);
    float acc = 0.f;
    #pragma unroll
    for (int c = j; c < NCHUNK; c += LPS) {   // 13 chunks per lane
        const float4 v = src[c];
        const float e0 = (float)(4 * c);
        float z;
        z = fmaf(e0,        dz, z0); acc = fmaf(__expf(fmaf(-0.5f * z, z, log_norm)), v.x, acc);
        z = fmaf(e0 + 1.f,  dz, z0); acc = fmaf(__expf(fmaf(-0.5f * z, z, log_norm)), v.y, acc);
        z = fmaf(e0 + 2.f,  dz, z0); acc = fmaf(__expf(fmaf(-0.5f * z, z, log_norm)), v.z, acc);
        z = fmaf(e0 + 3.f,  dz, z0); acc = fmaf(__expf(fmaf(-0.5f * z, z, log_norm)), v.w, acc);
    }

    // reduce 8 lanes -> sample
    acc += __shfl_xor(acc, 1);
    acc += __shfl_xor(acc, 2);
    acc += __shfl_xor(acc, 4);
    if (j == 0) out[n] = acc / denom;
}

extern "C" void kernel_launch(void* const* d_in, const int* in_sizes, int n_in,
                              void* d_out, int out_size, void* d_ws, size_t ws_size,
                              hipStream_t stream)
{
    const float* f0    = (const float*)d_in[1];   // d_in[0] = x (unused by the math)
    const float* table = (const float*)d_in[2];
    float* out = (float*)d_out;
    wt_kernel<<<dim3(NBLK), dim3(BLK), 0, stream>>>(f0, table, out);
}

// Round 3
// 9.931 us; speedup vs baseline: 1.1238x; 1.0460x over previous
//
#include <hip/hip_runtime.h>

// WavetableModel: out[n] = sum_t exp(log_norm - 0.5*z^2) * table[t] / (peak + 1e-8)
//   z = (t/4095 - mu_n)/sigma,  mu_n = frac((n+1)*|f0|),  sigma = 0.01+1e-8
// Gaussian sigma ~= 41 table indices; truncate at +-176 taps (+-4.3 sigma):
// truncation error <= ~2e-3 absolute vs threshold 2.05.
// Measured: kernel exec ~1.5-2.5us; dur_us floor ~8us is launch/graph overhead.

#define NS   32768
#define TS   4096
#define BLK  256
#define LPS  8               // lanes per sample
#define SPB  (BLK / LPS)     // 32 samples per block
#define NBLK (NS / SPB)      // 1024 blocks -> 4 blocks/CU, 16 waves/CU
#define HALF 176             // half-window in taps
#define NCHUNK 88            // float4 chunks per sample (352 taps)
#define TPAD 4352            // table + zero pad (max read = 3916+352 = 4268)

__global__ __launch_bounds__(BLK) void wt_kernel(const float* __restrict__ f0p,
                                                 const float* __restrict__ table,
                                                 float* __restrict__ out)
{
    __shared__ float tab[TPAD];
    const int tid = threadIdx.x;
    {
        const float4* t4 = (const float4*)table;
        float4* s4 = (float4*)tab;
        #pragma unroll
        for (int i = tid; i < TS / 4; i += BLK) s4[i] = t4[i];
        for (int i = TS / 4 + tid; i < TPAD / 4; i += BLK)
            s4[i] = make_float4(0.f, 0.f, 0.f, 0.f);
    }
    const float f0a = fabsf(f0p[0]);
    __syncthreads();

    const int g = blockIdx.x * BLK + tid;
    const int n = g >> 3;        // sample index
    const int j = g & (LPS - 1); // lane-within-sample

    const double sigma = 0.01 + 1e-8;
    const float  log_norm = 3.6862306527839187f;   // -ln(sigma) - 0.5*ln(2*pi)

    // mu exactly (double): frac((n+1)*|f0|)
    const double mu = fmod((double)(n + 1) * (double)f0a, 1.0);

    // normalizer: window value at nearest grid point
    const int tc = (int)(mu * 4095.0 + 0.5);
    const float zsf = (float)(((double)tc * (1.0 / 4095.0) - mu) / sigma);
    const float peak = __expf(fmaf(-0.5f * zsf, zsf, log_norm));
    const float denom = peak + 1e-8f;

    int t0 = tc - HALF;
    t0 = (t0 < 0) ? 0 : t0;
    t0 &= ~3;                    // float4 alignment

    const float dz = (float)(1.0 / (4095.0 * sigma));
    const float z0 = (float)(((double)t0 * (1.0 / 4095.0) - mu) / sigma);

    const float4* __restrict__ src = (const float4*)(tab + t0);
    float acc = 0.f;
    #pragma unroll
    for (int c = j; c < NCHUNK; c += LPS) {   // 11 chunks per lane
        const float4 v = src[c];
        const float e0 = (float)(4 * c);
        float z;
        z = fmaf(e0,        dz, z0); acc = fmaf(__expf(fmaf(-0.5f * z, z, log_norm)), v.x, acc);
        z = fmaf(e0 + 1.f,  dz, z0); acc = fmaf(__expf(fmaf(-0.5f * z, z, log_norm)), v.y, acc);
        z = fmaf(e0 + 2.f,  dz, z0); acc = fmaf(__expf(fmaf(-0.5f * z, z, log_norm)), v.z, acc);
        z = fmaf(e0 + 3.f,  dz, z0); acc = fmaf(__expf(fmaf(-0.5f * z, z, log_norm)), v.w, acc);
    }

    // reduce 8 lanes -> sample
    acc += __shfl_xor(acc, 1);
    acc += __shfl_xor(acc, 2);
    acc += __shfl_xor(acc, 4);
    if (j == 0) out[n] = acc / denom;
}

extern "C" void kernel_launch(void* const* d_in, const int* in_sizes, int n_in,
                              void* d_out, int out_size, void* d_ws, size_t ws_size,
                              hipStream_t stream)
{
    const float* f0    = (const float*)d_in[1];   // d_in[0] = x (unused by the math)
    const float* table = (const float*)d_in[2];
    float* out = (float*)d_out;
    wt_kernel<<<dim3(NBLK), dim3(BLK), 0, stream>>>(f0, table, out);
}

// Round 4
// 9.421 us; speedup vs baseline: 1.1846x; 1.0541x over previous
//
#include <hip/hip_runtime.h>

// WavetableModel: out[n] = sum_t exp(log_norm - 0.5*z^2) * table[t] / (peak+1e-8)
//   z=(t/4095-mu)/sigma, mu=frac((n+1)*|f0|), sigma=0.01+1e-8.
// Exp-free inner loop: w_k = e0 * R^k * g_k with
//   e0 = exp(log_norm - 0.5*z0^2)  (per sample, hoisted to epilogue)
//   R  = exp(-z0*dz)               (geometric chain: 1 mul/tap)
//   g_k= exp(-0.5*dz^2*k^2)        (sample-independent 288-entry LDS table)
// Window +-144 taps (3.51 sigma): truncation <=0.05 abs vs threshold 2.05.
// Measured: ~7us of dur_us is graph/launch overhead; exec was ~3us (exp-bound).

#define NS     32768
#define TS     4096
#define BLK    256
#define LPS    8                // lanes per sample
#define SPB    (BLK / LPS)      // 32 samples per block
#define NBLK   (NS / SPB)       // 1024 blocks
#define HALF   144              // half-window in taps
#define NCHUNK 72               // float4 chunks per sample (288 taps)
#define NTAP   (NCHUNK * 4)
#define TPAD   4352             // max read = 3948 + 287 = 4235 < 4352

__global__ __launch_bounds__(BLK) void wt_kernel(const float* __restrict__ f0p,
                                                 const float* __restrict__ table,
                                                 float* __restrict__ out)
{
    __shared__ __align__(16) float tab[TPAD];
    __shared__ __align__(16) float gtab[NTAP];
    const int tid = threadIdx.x;

    constexpr double SIGMA = 0.01 + 1e-8;
    constexpr double DZ    = 1.0 / (4095.0 * SIGMA);     // z step per tap
    constexpr float  GC    = (float)(-0.5 * DZ * DZ);    // g_k = exp(GC*k^2)
    const float log_norm = 3.6862306527839187f;          // -ln(sigma)-0.5*ln(2pi)

    {
        const float4* t4 = (const float4*)table;
        float4* s4 = (float4*)tab;
        #pragma unroll
        for (int i = tid; i < TS / 4; i += BLK) s4[i] = t4[i];
        for (int i = TS / 4 + tid; i < TPAD / 4; i += BLK)
            s4[i] = make_float4(0.f, 0.f, 0.f, 0.f);
        for (int k = tid; k < NTAP; k += BLK) {
            const float kf = (float)k;
            gtab[k] = __expf(GC * kf * kf);
        }
    }
    const float f0a = fabsf(f0p[0]);
    __syncthreads();

    const int g = blockIdx.x * BLK + tid;
    const int n = g >> 3;        // sample index
    const int j = g & (LPS - 1); // lane-within-sample

    // mu exactly (double): frac((n+1)*|f0|)
    const double mu = fmod((double)(n + 1) * (double)f0a, 1.0);

    // normalizer: window value at nearest grid point
    const int tc = (int)(mu * 4095.0 + 0.5);
    const float zsf = (float)(((double)tc * (1.0 / 4095.0) - mu) / SIGMA);
    const float peak = __expf(fmaf(-0.5f * zsf, zsf, log_norm));
    const float denom = peak + 1e-8f;

    int t0 = tc - HALF;
    t0 = (t0 < 0) ? 0 : t0;
    t0 &= ~3;                    // float4 alignment

    const double z0d = ((double)t0 * (1.0 / 4095.0) - mu) / SIGMA;
    const float  z0  = (float)z0d;
    const float  bb  = (float)(-z0d * DZ);               // ln R

    const float e0  = __expf(fmaf(-0.5f * z0, z0, log_norm));
    const float r1  = __expf(bb);                        // R
    const float r32 = __expf(bb * 32.0f);                // R^32 (lane chunk stride)
    float       rk  = __expf(bb * (float)(4 * j));       // R^(4j) start
    const float r2  = r1 * r1;
    const float r3  = r2 * r1;

    const float4* __restrict__ src = (const float4*)(tab + t0);
    const float4* __restrict__ gsrc = (const float4*)gtab;
    float acc = 0.f;
    #pragma unroll
    for (int c = j; c < NCHUNK; c += LPS) {   // 9 chunks per lane
        const float4 v  = src[c];
        const float4 gg = gsrc[c];
        const float w1 = rk * r1, w2 = rk * r2, w3 = rk * r3;
        acc = fmaf(rk * gg.x, v.x, acc);
        acc = fmaf(w1 * gg.y, v.y, acc);
        acc = fmaf(w2 * gg.z, v.z, acc);
        acc = fmaf(w3 * gg.w, v.w, acc);
        rk *= r32;
    }

    // reduce 8 lanes -> sample
    acc += __shfl_xor(acc, 1);
    acc += __shfl_xor(acc, 2);
    acc += __shfl_xor(acc, 4);
    if (j == 0) out[n] = acc * e0 / denom;
}

extern "C" void kernel_launch(void* const* d_in, const int* in_sizes, int n_in,
                              void* d_out, int out_size, void* d_ws, size_t ws_size,
                              hipStream_t stream)
{
    const float* f0    = (const float*)d_in[1];   // d_in[0] = x (unused by the math)
    const float* table = (const float*)d_in[2];
    float* out = (float*)d_out;
    wt_kernel<<<dim3(NBLK), dim3(BLK), 0, stream>>>(f0, table, out);
}